// Round 1
// baseline (526.470 us; speedup 1.0000x reference)
//
#include <hip/hip_runtime.h>

// Trilinear upsample x2, align_corners=True.
// in:  (1, 8, 128, 128, 128) f32
// out: (1, 8, 256, 256, 256) f32
// coord(o) = o * (S-1)/(S_out-1) = o * (127/255), computed in f32 to match
// the JAX reference bit-for-bit (same floor / min(i0+1,127) / frac).

#define C_IN 8
#define S_IN 128
#define S_OUT 256
#define RATIO (127.0f / 255.0f)   // compile-time f32, matches fl32(127/255)

__global__ __launch_bounds__(256) void upsample_trilinear_kernel(
    const float* __restrict__ x, float* __restrict__ out, int total4) {
    const int stride = gridDim.x * blockDim.x;
    for (int idx = blockIdx.x * blockDim.x + threadIdx.x; idx < total4; idx += stride) {
        // idx -> (c, d, h, w4); w = 4*w4 + j
        int t = idx;
        const int w4 = t & 63;   t >>= 6;   // 256/4 = 64 quads per row
        const int h  = t & 255;  t >>= 8;
        const int d  = t & 255;  t >>= 8;
        const int c  = t;

        // D axis
        float cd = (float)d * RATIO;
        int d0 = (int)floorf(cd);
        float fd = cd - (float)d0;
        int d1 = min(d0 + 1, S_IN - 1);
        // H axis
        float ch = (float)h * RATIO;
        int h0 = (int)floorf(ch);
        float fh = ch - (float)h0;
        int h1 = min(h0 + 1, S_IN - 1);

        const float* base = x + (size_t)c * (S_IN * S_IN * S_IN);
        const float* r00 = base + (d0 * S_IN + h0) * S_IN;
        const float* r01 = base + (d0 * S_IN + h1) * S_IN;
        const float* r10 = base + (d1 * S_IN + h0) * S_IN;
        const float* r11 = base + (d1 * S_IN + h1) * S_IN;

        const float gh = 1.0f - fh;
        const float gd = 1.0f - fd;

        float4 res;
        float* rp = &res.x;
        const int wbase = w4 * 4;
        #pragma unroll
        for (int j = 0; j < 4; ++j) {
            const int w = wbase + j;
            float cw = (float)w * RATIO;
            int w0 = (int)floorf(cw);
            float fw = cw - (float)w0;
            int w1 = min(w0 + 1, S_IN - 1);
            const float gw = 1.0f - fw;

            // W interp on each of the 4 corner rows (matches ref: W first)
            float a00 = r00[w0] * gw + r00[w1] * fw;
            float a01 = r01[w0] * gw + r01[w1] * fw;
            float a10 = r10[w0] * gw + r10[w1] * fw;
            float a11 = r11[w0] * gw + r11[w1] * fw;
            // H interp
            float a0 = a00 * gh + a01 * fh;
            float a1 = a10 * gh + a11 * fh;
            // D interp
            rp[j] = a0 * gd + a1 * fd;
        }
        reinterpret_cast<float4*>(out)[idx] = res;
    }
}

extern "C" void kernel_launch(void* const* d_in, const int* in_sizes, int n_in,
                              void* d_out, int out_size, void* d_ws, size_t ws_size,
                              hipStream_t stream) {
    const float* x = (const float*)d_in[0];
    float* out = (float*)d_out;
    const int total4 = out_size / 4;  // 33,554,432 float4 stores

    const int block = 256;
    const int grid = 2048;  // 8 blocks/CU x 256 CUs, grid-stride inside
    upsample_trilinear_kernel<<<grid, block, 0, stream>>>(x, out, total4);
}

// Round 2
// 281.881 us; speedup vs baseline: 1.8677x; 1.8677x over previous
//
#include <hip/hip_runtime.h>

// Trilinear upsample x2, align_corners=True.
// in:  (1, 8, 128, 128, 128) f32  -> out: (1, 8, 256, 256, 256) f32
//
// Key structure (exact in f32, r = fl32(127/255) = 0.498039216 < 0.5):
//   output w=2i   uses input cols {i-1, i}   (i>=1; i=0 handled by phantom)
//   output w=2i+1 uses input cols {i, i+1}
// => 16 consecutive W outputs (w=16k..16k+15) need cols 8k-1 .. 8k+8
//    (10 contiguous floats per corner-row) loaded as scalar + 2x float4 + scalar.
// Edge cases: col -1 and col 128 are clamped; their lerp weight is exactly 0
// (w=0: frac=1 -> weight on phantom col -1 is 0; w=255: cw==127.0 -> frac=0).
//
// Interp order: H and D first on the 10 columns, then W per output.
// (Reference does W,H,D; reordering is ~1-ulp different, threshold 0.105.)

#define S_IN 128
#define RATIO (127.0f / 255.0f)

__global__ __launch_bounds__(256) void upsample_trilinear_kernel(
    const float* __restrict__ x, float* __restrict__ out, int total16) {
    const int stride = gridDim.x * blockDim.x;
    for (int idx = blockIdx.x * blockDim.x + threadIdx.x; idx < total16; idx += stride) {
        // idx -> (c, d, h, w16); w = 16*w16 + j, j = 0..15
        int t = idx;
        const int w16 = t & 15;  t >>= 4;   // 256/16 per row
        const int h   = t & 255; t >>= 8;
        const int d   = t & 255; t >>= 8;
        const int c   = t;

        // D axis (runtime floor, matches reference arithmetic)
        float cd = (float)d * RATIO;
        int d0 = (int)floorf(cd);
        float fd = cd - (float)d0;
        int d1 = min(d0 + 1, S_IN - 1);
        // H axis
        float ch = (float)h * RATIO;
        int h0 = (int)floorf(ch);
        float fh = ch - (float)h0;
        int h1 = min(h0 + 1, S_IN - 1);

        const float gh = 1.0f - fh;
        const float gd = 1.0f - fd;

        const float* base = x + (size_t)c * (S_IN * S_IN * S_IN);
        const float* r00 = base + (d0 * S_IN + h0) * S_IN;
        const float* r01 = base + (d0 * S_IN + h1) * S_IN;
        const float* r10 = base + (d1 * S_IN + h0) * S_IN;
        const float* r11 = base + (d1 * S_IN + h1) * S_IN;

        const int b = 8 * w16 - 1;           // global col of local col 0
        const int c_lo = max(b, 0);          // clamp col -1 (weight 0)
        const int c_hi = min(b + 9, S_IN - 1); // clamp col 128 (weight 0)

        // Load 10 columns per corner-row: scalar + float4 + float4 + scalar.
        // b+1 = 8*w16 is 16B-aligned (row bases are multiples of 128 floats).
        float col[4][10];
        const float* rows[4] = {r00, r01, r10, r11};
        #pragma unroll
        for (int r = 0; r < 4; ++r) {
            const float* rp = rows[r];
            col[r][0] = rp[c_lo];
            float4 v0 = *reinterpret_cast<const float4*>(rp + b + 1);
            float4 v1 = *reinterpret_cast<const float4*>(rp + b + 5);
            col[r][1] = v0.x; col[r][2] = v0.y; col[r][3] = v0.z; col[r][4] = v0.w;
            col[r][5] = v1.x; col[r][6] = v1.y; col[r][7] = v1.z; col[r][8] = v1.w;
            col[r][9] = rp[c_hi];
        }

        // H then D lerp on the 10 columns -> one fused column vector.
        float colf[10];
        #pragma unroll
        for (int tcol = 0; tcol < 10; ++tcol) {
            float a0 = col[0][tcol] * gh + col[1][tcol] * fh;  // d0 plane
            float a1 = col[2][tcol] * gh + col[3][tcol] * fh;  // d1 plane
            colf[tcol] = a0 * gd + a1 * fd;
        }

        // W lerp per output. For output j: w = 16*w16 + j,
        //   i0 = (w>>1) - 1 + (w&1); local lo = (j>>1) + (j&1); corners {lo, lo+1}.
        float res[16];
        #pragma unroll
        for (int j = 0; j < 16; ++j) {
            const int w = 16 * w16 + j;
            const int lo = (j >> 1) + (j & 1);          // compile-time per j
            const float i0f = (float)(b + lo);          // == (w>>1)-1+(w&1)
            float cw = (float)w * RATIO;
            float fw = cw - i0f;
            res[j] = colf[lo] * (1.0f - fw) + colf[lo + 1] * fw;
        }

        // 4 coalesced float4 stores (64 contiguous bytes per thread).
        float4* o4 = reinterpret_cast<float4*>(out) + (size_t)idx * 4;
        #pragma unroll
        for (int q = 0; q < 4; ++q) {
            float4 v;
            v.x = res[q * 4 + 0]; v.y = res[q * 4 + 1];
            v.z = res[q * 4 + 2]; v.w = res[q * 4 + 3];
            o4[q] = v;
        }
    }
}

extern "C" void kernel_launch(void* const* d_in, const int* in_sizes, int n_in,
                              void* d_out, int out_size, void* d_ws, size_t ws_size,
                              hipStream_t stream) {
    const float* x = (const float*)d_in[0];
    float* out = (float*)d_out;
    const int total16 = out_size / 16;  // 8,388,608 threads-worth of work

    const int block = 256;
    const int grid = 2048;  // grid-stride, 16 iterations per thread
    upsample_trilinear_kernel<<<grid, block, 0, stream>>>(x, out, total16);
}

// Round 3
// 220.667 us; speedup vs baseline: 2.3858x; 1.2774x over previous
//
#include <hip/hip_runtime.h>

// Trilinear upsample x2, align_corners=True, f32.
// in:  (1, 8, 128, 128, 128) -> out: (1, 8, 256, 256, 256)
//
// Closed-form index structure (exact in f32, R = fl32(127/255) < 0.5):
//   output 2k   uses inputs {k-1, k},  frac = fl(2k*R) - (k-1)   (k=0: frac==1.0
//               exactly -> weight on clamped phantom row -1 is exactly 0)
//   output 2k+1 uses inputs {k, k+1},  frac = fl((2k+1)*R) - k   (k=127: frac==0
//               exactly -> weight on clamped phantom row 128 is exactly 0)
// Identical float ops to cd - floor(cd), so bit-identical fracs.
//
// Each thread computes a 2(D) x 2(H) x 16(W) output block from a
// 3 x 3 x 10 input neighborhood: 36 load instrs / 64 outputs, W-frac math
// shared across the 4 output rows.

#define S_IN 128
#define RATIO (127.0f / 255.0f)

__global__ __launch_bounds__(256) void upsample_trilinear_blk(
    const float* __restrict__ x, float* __restrict__ out) {
    const int t = blockIdx.x * 256 + threadIdx.x;
    const int w16 = t & 15;           // 16 w-quads of 16 outputs each
    const int q   = (t >> 4) & 127;   // h output-pair index
    const int p   = (t >> 11) & 127;  // d output-pair index
    const int c   = t >> 18;          // channel 0..7

    // Per-axis fracs for the two outputs of each pair.
    const float fd0 = (float)(2 * p) * RATIO - (float)(p - 1);
    const float fd1 = (float)(2 * p + 1) * RATIO - (float)p;
    const float fh0 = (float)(2 * q) * RATIO - (float)(q - 1);
    const float fh1 = (float)(2 * q + 1) * RATIO - (float)q;

    const int din[3] = {max(p - 1, 0), p, min(p + 1, S_IN - 1)};
    const int hin[3] = {max(q - 1, 0), q, min(q + 1, S_IN - 1)};

    const int b    = 8 * w16 - 1;              // global col of local col 0
    const int c_lo = max(b, 0);                // weight-0 phantom at w16==0
    const int c_hi = min(b + 9, S_IN - 1);     // weight-0 phantom at w16==15

    const float* base = x + (size_t)c * (S_IN * S_IN * S_IN);

    // Load 9 corner rows x 10 columns: scalar + 2x aligned float4 + scalar.
    float col[3][3][10];
    #pragma unroll
    for (int dr = 0; dr < 3; ++dr) {
        #pragma unroll
        for (int hr = 0; hr < 3; ++hr) {
            const float* rp = base + (din[dr] * S_IN + hin[hr]) * S_IN;
            float* cp = col[dr][hr];
            cp[0] = rp[c_lo];
            float4 v0 = *reinterpret_cast<const float4*>(rp + b + 1);
            float4 v1 = *reinterpret_cast<const float4*>(rp + b + 5);
            cp[1] = v0.x; cp[2] = v0.y; cp[3] = v0.z; cp[4] = v0.w;
            cp[5] = v1.x; cp[6] = v1.y; cp[7] = v1.z; cp[8] = v1.w;
            cp[9] = rp[c_hi];
        }
    }

    // W fracs, shared across the 4 output rows of this thread.
    float fw[16];
    #pragma unroll
    for (int j = 0; j < 16; ++j) {
        const int w  = 16 * w16 + j;
        const int lo = (j >> 1) + (j & 1);     // local lower corner, compile-time
        fw[j] = (float)w * RATIO - (float)(b + lo);
    }

    // 4 output rows: (dout, hout) in {0,1}^2.
    #pragma unroll
    for (int dout = 0; dout < 2; ++dout) {
        const float fd = dout ? fd1 : fd0;
        const float gd = 1.0f - fd;
        #pragma unroll
        for (int hout = 0; hout < 2; ++hout) {
            const float fh = hout ? fh1 : fh0;
            const float gh = 1.0f - fh;

            // H then D lerp of the 10 columns (rows dout/dout+1, hout/hout+1).
            float colf[10];
            #pragma unroll
            for (int tc = 0; tc < 10; ++tc) {
                float a0 = col[dout][hout][tc] * gh + col[dout][hout + 1][tc] * fh;
                float a1 = col[dout + 1][hout][tc] * gh + col[dout + 1][hout + 1][tc] * fh;
                colf[tc] = a0 * gd + a1 * fd;
            }

            // W lerp: 16 outputs -> 4 coalesced float4 stores.
            const int dg = 2 * p + dout;
            const int hg = 2 * q + hout;
            float4* o4 = reinterpret_cast<float4*>(
                out + (((size_t)(c * 256 + dg) * 256 + hg) * 256 + 16 * w16));
            #pragma unroll
            for (int qd = 0; qd < 4; ++qd) {
                float4 v;
                float* vp = &v.x;
                #pragma unroll
                for (int e = 0; e < 4; ++e) {
                    const int j  = qd * 4 + e;
                    const int lo = (j >> 1) + (j & 1);
                    vp[e] = colf[lo] * (1.0f - fw[j]) + colf[lo + 1] * fw[j];
                }
                o4[qd] = v;
            }
        }
    }
}

extern "C" void kernel_launch(void* const* d_in, const int* in_sizes, int n_in,
                              void* d_out, int out_size, void* d_ws, size_t ws_size,
                              hipStream_t stream) {
    const float* x = (const float*)d_in[0];
    float* out = (float*)d_out;
    // 8 c * 128 p * 128 q * 16 w16 = 2,097,152 threads, 64 outputs each.
    const int block = 256;
    const int grid = 8192;
    upsample_trilinear_blk<<<grid, block, 0, stream>>>(x, out);
}

// Round 4
// 137.529 us; speedup vs baseline: 3.8281x; 1.6045x over previous
//
#include <hip/hip_runtime.h>

// Trilinear upsample x2, align_corners=True, f32.
// in:  (1, 8, 128, 128, 128) -> out: (1, 8, 256, 256, 256)
//
// Index structure (exact in f32, R = fl32(127/255) = 0.49803918600...):
//   output 2k   uses inputs {k-1, k},  frac = fl(2k*R) - (k-1)
//   output 2k+1 uses inputs {k, k+1},  frac = fl((2k+1)*R) - k
// (k=0: frac == 1.0 exactly -> phantom lower corner has weight exactly 0;
//  k=127 upper edge: frac = -7.6e-6, phantom contributes ~5e-5 — validated
//  in rounds 1-2, threshold 0.105.)
//
// Thread layout: lane a in [0,64) of each wave owns outputs w = 4a..4a+3 of
// one (2 x 2) D/H output block. Loads are float2 {2a, 2a+1} per corner row:
// 64 lanes x 8B = 512B contiguous per instruction. Each input column is
// H/D-lerped by exactly one lane; halo fused-columns (2a-1, 2a+2) come from
// neighbor lanes via shuffles. Stores: 4 x float4, 1KB contiguous per instr.

#define S_IN 128
#define RATIO (127.0f / 255.0f)

__global__ __launch_bounds__(256) void upsample_trilinear_v3(
    const float* __restrict__ x, float* __restrict__ out) {
    const int t = blockIdx.x * 256 + threadIdx.x;
    const int a = t & 63;            // w-quad: outputs 4a..4a+3
    const int q = (t >> 6) & 127;    // h output-pair
    const int p = (t >> 13) & 127;   // d output-pair
    const int c = t >> 20;           // channel 0..7

    // Per-axis fracs (bit-identical to reference's coords - floor(coords)).
    const float fd0 = (float)(2 * p) * RATIO - (float)(p - 1);
    const float fd1 = (float)(2 * p + 1) * RATIO - (float)p;
    const float fh0 = (float)(2 * q) * RATIO - (float)(q - 1);
    const float fh1 = (float)(2 * q + 1) * RATIO - (float)q;

    const int din[3] = {max(p - 1, 0), p, min(p + 1, S_IN - 1)};
    const int hin[3] = {max(q - 1, 0), q, min(q + 1, S_IN - 1)};

    const float* base = x + (size_t)c * (S_IN * S_IN * S_IN);

    // 9 corner rows x float2 (cols 2a, 2a+1) — fully coalesced, never OOB.
    float2 col[3][3];
    #pragma unroll
    for (int dr = 0; dr < 3; ++dr) {
        #pragma unroll
        for (int hr = 0; hr < 3; ++hr) {
            col[dr][hr] = *reinterpret_cast<const float2*>(
                base + (din[dr] * S_IN + hin[hr]) * S_IN + 2 * a);
        }
    }

    // H lerp once per (plane, h-pair): 3 x 2 float2 values.
    float2 hl[3][2];
    #pragma unroll
    for (int pl = 0; pl < 3; ++pl) {
        #pragma unroll
        for (int hp = 0; hp < 2; ++hp) {
            const float fh = hp ? fh1 : fh0;
            const float gh = 1.0f - fh;
            hl[pl][hp].x = col[pl][hp].x * gh + col[pl][hp + 1].x * fh;
            hl[pl][hp].y = col[pl][hp].y * gh + col[pl][hp + 1].y * fh;
        }
    }

    // W fracs for outputs w = 4a+j (shared by all 4 output rows).
    const float fw0 = (float)(4 * a)     * RATIO - (float)(2 * a - 1);
    const float fw1 = (float)(4 * a + 1) * RATIO - (float)(2 * a);
    const float fw2 = (float)(4 * a + 2) * RATIO - (float)(2 * a);
    const float fw3 = (float)(4 * a + 3) * RATIO - (float)(2 * a + 1);

    // 4 output rows: D lerp -> halo shuffle -> W lerp -> coalesced store.
    #pragma unroll
    for (int dout = 0; dout < 2; ++dout) {
        const float fd = dout ? fd1 : fd0;
        const float gd = 1.0f - fd;
        #pragma unroll
        for (int hp = 0; hp < 2; ++hp) {
            float2 colf;
            colf.x = hl[dout][hp].x * gd + hl[dout + 1][hp].x * fd;
            colf.y = hl[dout][hp].y * gd + hl[dout + 1][hp].y * fd;

            // Fused halo columns from neighbor lanes.
            // Lane 0's cm1 / lane 63's cp2 are self-values: finite, and
            // their lerp weights are exactly 0 / ~7e-6 (phantom columns).
            const float cm1 = __shfl_up(colf.y, 1);    // fused col 2a-1
            const float cp2 = __shfl_down(colf.x, 1);  // fused col 2a+2

            float4 v;
            v.x = cm1    * (1.0f - fw0) + colf.x * fw0;
            v.y = colf.x * (1.0f - fw1) + colf.y * fw1;
            v.z = colf.x * (1.0f - fw2) + colf.y * fw2;
            v.w = colf.y * (1.0f - fw3) + cp2    * fw3;

            const int dg = 2 * p + dout;
            const int hg = 2 * q + hp;
            *reinterpret_cast<float4*>(
                out + (((size_t)(c * 256 + dg) * 256 + hg) * 256 + 4 * a)) = v;
        }
    }
}

extern "C" void kernel_launch(void* const* d_in, const int* in_sizes, int n_in,
                              void* d_out, int out_size, void* d_ws, size_t ws_size,
                              hipStream_t stream) {
    const float* x = (const float*)d_in[0];
    float* out = (float*)d_out;
    // 8 c * 128 p * 128 q * 64 a = 8,388,608 threads, 16 outputs each.
    const int block = 256;
    const int grid = 32768;
    upsample_trilinear_v3<<<grid, block, 0, stream>>>(x, out);
}

// Round 5
// 92.599 us; speedup vs baseline: 5.6855x; 1.4852x over previous
//
#include <hip/hip_runtime.h>

// Trilinear upsample x2, align_corners=True, f32.
// in:  (1, 8, 128, 128, 128) -> out: (1, 8, 256, 256, 256)
//
// Index structure (exact in f32, R = fl32(127/255) = 0.49803918600...):
//   output 2k   uses inputs {k-1, k},  frac = fl(2k*R) - (k-1)
//   output 2k+1 uses inputs {k, k+1},  frac = fl((2k+1)*R) - k
// (k=0: frac == 1.0 exactly -> phantom lower corner has weight exactly 0;
//  k=127 upper edge: frac = -7.6e-6, phantom contributes ~5e-5 — validated
//  rounds 1-3, threshold 0.105.)
//
// Thread layout: lane a in [0,64) of each wave owns outputs w = 4a..4a+3 of
// one (2 x 2) D/H output block. Loads are float2 {2a, 2a+1} per corner row:
// 64 lanes x 8B = 512B contiguous per instruction. Halo fused-columns
// (2a-1, 2a+2) via shuffles. Stores: 4 x float4 nontemporal (nt) — the
// 537 MB write-once stream must not allocate in L2/L3, so the 67 MB input
// stays L3-resident for the 9x-overlapping corner-row reads.

#define S_IN 128
#define RATIO (127.0f / 255.0f)

typedef float f32x4 __attribute__((ext_vector_type(4)));

__global__ __launch_bounds__(256) void upsample_trilinear_v4(
    const float* __restrict__ x, float* __restrict__ out) {
    const int t = blockIdx.x * 256 + threadIdx.x;
    const int a = t & 63;            // w-quad: outputs 4a..4a+3
    const int q = (t >> 6) & 127;    // h output-pair
    const int p = (t >> 13) & 127;   // d output-pair
    const int c = t >> 20;           // channel 0..7

    // Per-axis fracs (bit-identical to reference's coords - floor(coords)).
    const float fd0 = (float)(2 * p) * RATIO - (float)(p - 1);
    const float fd1 = (float)(2 * p + 1) * RATIO - (float)p;
    const float fh0 = (float)(2 * q) * RATIO - (float)(q - 1);
    const float fh1 = (float)(2 * q + 1) * RATIO - (float)q;

    const int din[3] = {max(p - 1, 0), p, min(p + 1, S_IN - 1)};
    const int hin[3] = {max(q - 1, 0), q, min(q + 1, S_IN - 1)};

    const float* base = x + (size_t)c * (S_IN * S_IN * S_IN);

    // 9 corner rows x float2 (cols 2a, 2a+1) — fully coalesced, never OOB.
    float2 col[3][3];
    #pragma unroll
    for (int dr = 0; dr < 3; ++dr) {
        #pragma unroll
        for (int hr = 0; hr < 3; ++hr) {
            col[dr][hr] = *reinterpret_cast<const float2*>(
                base + (din[dr] * S_IN + hin[hr]) * S_IN + 2 * a);
        }
    }

    // H lerp once per (plane, h-pair).
    float2 hl[3][2];
    #pragma unroll
    for (int pl = 0; pl < 3; ++pl) {
        #pragma unroll
        for (int hp = 0; hp < 2; ++hp) {
            const float fh = hp ? fh1 : fh0;
            const float gh = 1.0f - fh;
            hl[pl][hp].x = col[pl][hp].x * gh + col[pl][hp + 1].x * fh;
            hl[pl][hp].y = col[pl][hp].y * gh + col[pl][hp + 1].y * fh;
        }
    }

    // W fracs for outputs w = 4a+j (shared by all 4 output rows).
    const float fw0 = (float)(4 * a)     * RATIO - (float)(2 * a - 1);
    const float fw1 = (float)(4 * a + 1) * RATIO - (float)(2 * a);
    const float fw2 = (float)(4 * a + 2) * RATIO - (float)(2 * a);
    const float fw3 = (float)(4 * a + 3) * RATIO - (float)(2 * a + 1);

    // 4 output rows: D lerp -> halo shuffle -> W lerp -> nt store.
    #pragma unroll
    for (int dout = 0; dout < 2; ++dout) {
        const float fd = dout ? fd1 : fd0;
        const float gd = 1.0f - fd;
        #pragma unroll
        for (int hp = 0; hp < 2; ++hp) {
            float2 colf;
            colf.x = hl[dout][hp].x * gd + hl[dout + 1][hp].x * fd;
            colf.y = hl[dout][hp].y * gd + hl[dout + 1][hp].y * fd;

            // Fused halo columns from neighbor lanes (edge lanes: weight-0
            // phantoms, self-value is finite -> exact per the edge identity).
            const float cm1 = __shfl_up(colf.y, 1);    // fused col 2a-1
            const float cp2 = __shfl_down(colf.x, 1);  // fused col 2a+2

            f32x4 v;
            v.x = cm1    * (1.0f - fw0) + colf.x * fw0;
            v.y = colf.x * (1.0f - fw1) + colf.y * fw1;
            v.z = colf.x * (1.0f - fw2) + colf.y * fw2;
            v.w = colf.y * (1.0f - fw3) + cp2    * fw3;

            const int dg = 2 * p + dout;
            const int hg = 2 * q + hp;
            f32x4* dst = reinterpret_cast<f32x4*>(
                out + (((size_t)(c * 256 + dg) * 256 + hg) * 256 + 4 * a));
            __builtin_nontemporal_store(v, dst);
        }
    }
}

extern "C" void kernel_launch(void* const* d_in, const int* in_sizes, int n_in,
                              void* d_out, int out_size, void* d_ws, size_t ws_size,
                              hipStream_t stream) {
    const float* x = (const float*)d_in[0];
    float* out = (float*)d_out;
    // 8 c * 128 p * 128 q * 64 a = 8,388,608 threads, 16 outputs each.
    const int block = 256;
    const int grid = 32768;
    upsample_trilinear_v4<<<grid, block, 0, stream>>>(x, out);
}